// Round 11
// baseline (436.570 us; speedup 1.0000x reference)
//
#include <hip/hip_runtime.h>
#include <hip/hip_bf16.h>

#define BATCH 2048
#define IN_DIM 128
#define GRIDN 128
#define HID 256
#define DEPTH 7

typedef unsigned int u32;
typedef __attribute__((ext_vector_type(8))) short short8;
typedef __attribute__((ext_vector_type(4))) float floatx4;
typedef __attribute__((ext_vector_type(16))) float floatx16;

// ---------------- ws layout (bytes) ----------------
// fs2: bf16, 32x32x16-frag-ordered: [slab:896][nhalf:2][ks:4][v:4][kk:2][l:64][e:8]
// element (h,g): h = nhalf*128 + v*32 + (l&31); g = ks*32 + kk*16 + (l>>5)*8 + e
#define OFF_FST   ((size_t)0)
#define SZ_FST    ((size_t)7*128*256*128*2)       // 58,720,256
#define OFF_ZT    (OFF_FST + SZ_FST)              // fp32 z_t [128][2048]
#define SZ_ZT     ((size_t)BATCH*IN_DIM*4)
#define OFF_HPRE  (OFF_ZT + SZ_ZT)                // fp32 h_pre [2048][256]
#define SZ_HPRE   ((size_t)BATCH*HID*4)
#define OFF_STATS (OFF_HPRE + SZ_HPRE)            // fp32 stats 3*[512]
#define SZ_STATS  ((size_t)3*2*HID*4)
#define OFF_KEYS  (OFF_STATS + SZ_STATS)          // u32 keys [256]
#define SZ_KEYS   ((size_t)256*4)
#define OFF_CW    (OFF_KEYS + SZ_KEYS)            // (unused)
#define SZ_CW     ((size_t)32)
#define OFF_Y1    (OFF_CW + SZ_CW)
#define SZ_Y      ((size_t)BATCH*HID*4)
#define OFF_Y2    (OFF_Y1 + SZ_Y)
#define OFF_Y3    (OFF_Y2 + SZ_Y)

#define FENCE __asm__ volatile("" ::: "memory")
#define WAITV(c) do { __builtin_amdgcn_s_waitcnt(c); FENCE; } while (0)
#define BARR do { FENCE; __builtin_amdgcn_s_barrier(); FENCE; } while (0)
#define VM8 0x0F78
#define VM4 0x0F74
#define VM0 0x0F70

__device__ __forceinline__ void gload_lds16(const void* g, void* l) {
  __builtin_amdgcn_global_load_lds(
      (const __attribute__((address_space(1))) u32*)g,
      (__attribute__((address_space(3))) u32*)l, 16, 0, 0);
}

__device__ __forceinline__ u32 pack2_bf16(float lo, float hi) {
  __hip_bfloat162 b2;
  b2.x = __float2bfloat16(lo);
  b2.y = __float2bfloat16(hi);
  return *reinterpret_cast<u32*>(&b2);
}

// truncating bf16x2 pack: one v_perm_b32 (lo = hi16(a), hi = hi16(b))
__device__ __forceinline__ u32 pk_trunc(float a, float b) {
  return __builtin_amdgcn_perm(__float_as_uint(b), __float_as_uint(a), 0x07060302u);
}

// relu(v) for v in (-1,1): med3(v,0,1) == clamp -> folds into v_sub_f32 clamp
__device__ __forceinline__ float reluc(float v) {
  return __builtin_amdgcn_fmed3f(v, 0.0f, 1.0f);
}

__device__ __forceinline__ float gelu_exact(float x) {
  return 0.5f * x * (1.0f + erff(x * 0.70710678118654752f));
}

// ---------------- fused convert + prep1 (independent roles, one dispatch) ----
// Blocks [0,896): fs fp32 [d,i,g,h] -> cd*bf16, 32x32x16-frag-ordered fs2.
//   3x16KB triple-buffered DMA pipeline over 8 16-row phases; counted vmcnt(4).
//   New layout needs NO source swizzle: pack reads are naturally 2-way (free).
// Blocks [896,960): prep1 role — per-feature min/max monotone-key atomics.
__global__ void convert_prep1_kernel(const float* __restrict__ fs,
                                     const float* __restrict__ depth_scores,
                                     const float* __restrict__ x,
                                     u32* __restrict__ keys,
                                     __hip_bfloat16* __restrict__ fs2) {
  __shared__ __align__(16) float lds3[3 * 16 * 256];   // 48KB
  int bid = blockIdx.x;
  int t = threadIdx.x;

  if (bid >= DEPTH * IN_DIM) {
    // ---- prep1 role ----
    int pb = bid - DEPTH * IN_DIM;     // [0,64)
    int base = pb * 256 + t;
    float mn = 1e30f, mx = -1e30f;
#pragma unroll
    for (int j = 0; j < 16; ++j) {
      float v = x[base + j * 16384];   // same feature i each iter
      mn = fminf(mn, v); mx = fmaxf(mx, v);
    }
    float* smn = lds3; float* smx = lds3 + 256;
    smn[t] = mn; smx[t] = mx;
    __syncthreads();
    if (t < 128) {
      mn = fminf(smn[t], smn[t + 128]);
      mx = fmaxf(smx[t], smx[t + 128]);
      int i = base & 127;
      atomicMax(&keys[i], 0x7FFFFFFFu - __float_as_uint(mn));
      atomicMax(&keys[128 + i], __float_as_uint(mx));
    }
    return;
  }

  // ---- convert role ----
  int slab = bid;                      // d*128 + i
  int w = t >> 6, l = t & 63;
  int d = slab >> 7;
  // local softmax-cumsum: cd = sum_{i>=d} softmax(ds)[i]
  float m = -1e30f; float ds[DEPTH];
#pragma unroll
  for (int i = 0; i < DEPTH; ++i) { ds[i] = depth_scores[i]; m = fmaxf(m, ds[i]); }
  float sum = 0.f, tail = 0.f;
#pragma unroll
  for (int i = 0; i < DEPTH; ++i) {
    float e = expf(ds[i] - m);
    sum += e;
    if (i >= d) tail += e;
  }
  float cd = tail / sum;

  const float* src = fs + (size_t)slab * (GRIDN * HID);
  char* dstb = (char*)fs2 + (size_t)slab * 65536;

  // DMA phase p: g-rows p*16 + (w*4+i) -> buf p%3 slot, linear (no swizzle)
  auto dmaPhase = [&](int p) {
    const float* s0 = src + (size_t)p * 16 * HID;
    char* bb = (char*)lds3 + (p % 3) * 16384;
#pragma unroll
    for (int i = 0; i < 4; ++i) {
      int sl = w * 4 + i;
      gload_lds16(s0 + (size_t)sl * HID + l * 4, bb + sl * 1024);
    }
  };
  // pack phase p (ks = p>>1, kk = p&1): emit 512 16B frag-slots (2/thread).
  // slot (nh, v, lq): reads 8 rows rr = (lq>>5)*8+j at col h = nh*128+v*32+(lq&31)
  auto packPhase = [&](int p) {
    int ks = p >> 1, hh = p & 1;
    const float* bb = lds3 + (p % 3) * 4096;   // floats
#pragma unroll
    for (int it = 0; it < 2; ++it) {
      int task = t + it * 256;        // [0,512)
      int nh = task >> 8;
      int q = task & 255;
      int v = q >> 6, lq = q & 63;
      int h = nh * 128 + v * 32 + (lq & 31);
      const float* rp = bb + ((lq >> 5) * 8) * 256 + h;
      uint4 pk4;
      pk4.x = pack2_bf16(cd * rp[0 * 256], cd * rp[1 * 256]);
      pk4.y = pack2_bf16(cd * rp[2 * 256], cd * rp[3 * 256]);
      pk4.z = pack2_bf16(cd * rp[4 * 256], cd * rp[5 * 256]);
      pk4.w = pack2_bf16(cd * rp[6 * 256], cd * rp[7 * 256]);
      size_t off = (size_t)nh * 32768 + (size_t)ks * 8192 + (size_t)v * 2048 +
                   (size_t)hh * 1024 + (size_t)lq * 16;
      *(uint4*)(dstb + off) = pk4;
    }
  };

  dmaPhase(0); dmaPhase(1); FENCE;
#pragma unroll 1
  for (int p = 0; p < 6; ++p) {
    WAITV(VM4); BARR;                  // dma(p) in for all waves
    dmaPhase(p + 2); FENCE;            // buf (p+2)%3: last read phase p-1, safe
    packPhase(p);
  }
  WAITV(VM4); BARR; packPhase(6);
  WAITV(VM0); BARR; packPhase(7);
}

// ---------------- prep2: z_t[i][b] via LDS transpose (256B contiguous stores)
__global__ void prep2_kernel(const float* __restrict__ x, const u32* __restrict__ keys,
                             float* __restrict__ z_t) {
  __shared__ float lds[128 * 65];
  int t = threadIdx.x;
  int b0 = blockIdx.x * 64;
#pragma unroll
  for (int q = 0; q < 32; ++q) {
    int idx = q * 256 + t;              // [0, 8192)
    int b = idx >> 7, i = idx & 127;
    lds[i * 65 + b] = x[(size_t)(b0 + b) * IN_DIM + i];
  }
  __syncthreads();
#pragma unroll
  for (int q = 0; q < 32; ++q) {
    int idx = q * 256 + t;
    int ii = idx >> 6, bb = idx & 63;
    float mnv = __uint_as_float(0x7FFFFFFFu - keys[ii]);
    float mxv = __uint_as_float(keys[128 + ii]);
    float v = (lds[ii * 65 + bb] - mnv) * (1.0f / (mxv - mnv + 1e-6f));
    z_t[(size_t)ii * BATCH + b0 + bb] = v;
  }
}

// ---------------- big GEMM: h_pre += relu(z-grids) @ (c_d*fs) ----------------
// Round-7 schedule (shared triple buffer, one barrier/step, counted vmcnt(8))
// switched to 32x32x16 MFMA: 16 MFMA/wave/step (was 32) at 4061 FLOP/cyc
// (was 3378) — halves MFMA issue slots, +15% matrix-pipe ceiling. Same acc
// budget (2x4x16=128), same staging (8KB/step), same ledger (zg = 2z + 4xg
// float4 = 6 VMEM). A: row=l&31, k=(l>>5)*8+e; B: col=l&31, same k;
// C/D: col=l&31, row=(reg&3)+8*(reg>>2)+4*(l>>5)  [m74/m101 verified].
// bf frags read 4+4 (halves) to keep VGPR ~240 (2 waves/SIMD).
__launch_bounds__(256, 2)
__global__ void gemm_kernel(const float* __restrict__ z_t,
                            const float* __restrict__ grids,
                            const __hip_bfloat16* __restrict__ fs2,
                            float* __restrict__ h_pre) {
  __shared__ __align__(16) char lds[24576];   // 3 x 8KB shared triple buffer

  int bx = blockIdx.x;
  int xcd = bx & 7;
  int t6 = bx >> 3;                 // [0,64)
  int cg2 = t6 >> 4;                // [0,4)
  int jb2 = t6 & 15;                // [0,16): mtile(256) * nhalf
  int chunk = xcd + 8 * cg2;        // [0,32); same-XCD blocks share fs2 chunk
  int slab0 = chunk * 28;
  int mt = jb2 >> 1;                // [0,8) 256-row mtile
  int nh = jb2 & 1;                 // n-half of output

  int tid = threadIdx.x;
  int w = tid >> 6, l = tid & 63;
  int l31 = l & 31, lhi = l >> 5;
  int mbase = mt * 256 + w * 64;    // each wave: distinct 64-row strip
  int nbase = nh * 128;

  floatx16 acc[2][4];
#pragma unroll
  for (int a = 0; a < 2; ++a)
#pragma unroll
    for (int b = 0; b < 4; ++b) acc[a][b] = (floatx16)0.f;

  // this wave's 2KB staging slice base (per-lane src; dest lane-offset is HW)
  const char* fsb = (const char*)fs2 + (size_t)slab0 * 65536 + (size_t)nh * 32768 +
                    (size_t)w * 2048 + (size_t)l * 16;

  // stage full step u (block: 8KB; this wave: 2KB = 2 x 1KB) -> buf[bufIdx]
  auto stage8 = [&](int u, int bufIdx) {
    const char* srcb = fsb + (size_t)(u >> 2) * 65536 + (size_t)(u & 3) * 8192;
    char* dst = lds + bufIdx * 8192 + w * 2048;
    gload_lds16(srcb, dst);
    gload_lds16(srcb + 1024, dst + 1024);
  };

  // z/g regs, parity by step (even=A, odd=B): 2 z + 16 g floats per parity
  float zA0, zA1, zB0, zB1;
  float4 gA0, gA0b, gA1, gA1b, gB0, gB0b, gB1, gB1b;
  auto zgload = [&](int s, float& z0, float& z1, float4& G0, float4& G0b,
                    float4& G1, float4& G1b) {
    int slab = slab0 + (s >> 2);
    int iz = slab & 127;
    const float* zp = z_t + (size_t)iz * BATCH + mbase + l31;
    z0 = zp[0]; z1 = zp[32];
    const float* gp = grids + (size_t)slab * GRIDN + (s & 3) * 32 + lhi * 8;
    G0 = *(const float4*)gp;        // kk=0, e=0..3
    G0b = *(const float4*)(gp + 4); // kk=0, e=4..7
    G1 = *(const float4*)(gp + 16); // kk=1, e=0..3
    G1b = *(const float4*)(gp + 20);// kk=1, e=4..7
  };

  short8 af[4];                     // af[u*2+kk]
  short8 bf4[4];                    // half of the step's B frags
  auto rdhalf = [&](int bufIdx, int h2) {
    const char* bp = lds + bufIdx * 8192 + (size_t)(h2 * 2) * 2048 + l * 16;
    bf4[0] = *(const short8*)(bp);
    bf4[1] = *(const short8*)(bp + 1024);
    bf4[2] = *(const short8*)(bp + 2048);
    bf4[3] = *(const short8*)(bp + 3072);
  };
  // A fragments: relu(z - grid) via sub+clamp, truncating bf16 pack
  auto afgen = [&](float z0, float z1, const float4 G0, const float4 G0b,
                   const float4 G1, const float4 G1b) {
#pragma unroll
    for (int u = 0; u < 2; ++u) {
      float zu = u ? z1 : z0;
      union { uint4 q; short8 s8; } p0, p1;
      p0.q.x = pk_trunc(reluc(zu - G0.x), reluc(zu - G0.y));
      p0.q.y = pk_trunc(reluc(zu - G0.z), reluc(zu - G0.w));
      p0.q.z = pk_trunc(reluc(zu - G0b.x), reluc(zu - G0b.y));
      p0.q.w = pk_trunc(reluc(zu - G0b.z), reluc(zu - G0b.w));
      p1.q.x = pk_trunc(reluc(zu - G1.x), reluc(zu - G1.y));
      p1.q.y = pk_trunc(reluc(zu - G1.z), reluc(zu - G1.w));
      p1.q.z = pk_trunc(reluc(zu - G1b.x), reluc(zu - G1b.y));
      p1.q.w = pk_trunc(reluc(zu - G1b.z), reluc(zu - G1b.w));
      af[u * 2 + 0] = p0.s8;
      af[u * 2 + 1] = p1.s8;
    }
  };
  auto mfhalf = [&](int h2) {
    __builtin_amdgcn_s_setprio(1);
#pragma unroll
    for (int u = 0; u < 2; ++u)
#pragma unroll
      for (int vv = 0; vv < 2; ++vv) {
        int v = h2 * 2 + vv;
        acc[u][v] = __builtin_amdgcn_mfma_f32_32x32x16_bf16(af[u * 2 + 0], bf4[vv * 2 + 0], acc[u][v], 0, 0, 0);
        acc[u][v] = __builtin_amdgcn_mfma_f32_32x32x16_bf16(af[u * 2 + 1], bf4[vv * 2 + 1], acc[u][v], 0, 0, 0);
      }
    __builtin_amdgcn_s_setprio(0);
  };

// full step: wait slices+zg of S -> barrier; stage S+2; read half0; gen A;
// prefetch zg(S+2); MFMA half0; read half1; MFMA half1.
#define STEP_FULL(S, BUF, STBUF, Z0, Z1, G0, G0b, G1, G1b)                     \
  do {                                                                         \
    WAITV(VM8); BARR;                                                          \
    stage8((S) + 2, (STBUF)); FENCE;                                           \
    rdhalf(BUF, 0);                                                            \
    afgen(Z0, Z1, G0, G0b, G1, G1b);                                           \
    zgload((S) + 2, Z0, Z1, G0, G0b, G1, G1b); FENCE;                          \
    mfhalf(0);                                                                 \
    rdhalf(BUF, 1);                                                            \
    mfhalf(1);                                                                 \
  } while (0)

  // prologue: queue = [St0:2, Zg0:6, St1:2, Zg1:6] = 16 in flight
  stage8(0, 0); FENCE;
  zgload(0, zA0, zA1, gA0, gA0b, gA1, gA1b); FENCE;
  stage8(1, 1); FENCE;
  zgload(1, zB0, zB1, gB0, gB0b, gB1, gB1b); FENCE;

  // main loop: steps 0..107, buf = s%3, zg parity = s%2; uniform vmcnt(8)
#pragma unroll 1
  for (int s0 = 0; s0 < 108; s0 += 6) {
    STEP_FULL(s0 + 0, 0, 2, zA0, zA1, gA0, gA0b, gA1, gA1b);
    STEP_FULL(s0 + 1, 1, 0, zB0, zB1, gB0, gB0b, gB1, gB1b);
    STEP_FULL(s0 + 2, 2, 1, zA0, zA1, gA0, gA0b, gA1, gA1b);
    STEP_FULL(s0 + 3, 0, 2, zB0, zB1, gB0, gB0b, gB1, gB1b);
    STEP_FULL(s0 + 4, 1, 0, zA0, zA1, gA0, gA0b, gA1, gA1b);
    STEP_FULL(s0 + 5, 2, 1, zB0, zB1, gB0, gB0b, gB1, gB1b);
  }

  // ---- tail ----
  STEP_FULL(108, 0, 2, zA0, zA1, gA0, gA0b, gA1, gA1b);
  STEP_FULL(109, 1, 0, zB0, zB1, gB0, gB0b, gB1, gB1b);
  // s=110 (buf2, A): queue [St110:2,Zg110:6,St111:2,Zg111:6] -> vmcnt(8)
  WAITV(VM8); BARR;
  rdhalf(2, 0);
  afgen(zA0, zA1, gA0, gA0b, gA1, gA1b);
  mfhalf(0);
  rdhalf(2, 1);
  mfhalf(1);
  // s=111 (buf0, B): queue [St111:2,Zg111:6] -> vmcnt(0)
  WAITV(VM0); BARR;
  rdhalf(0, 0);
  afgen(zB0, zB1, gB0, gB0b, gB1, gB1b);
  mfhalf(0);
  rdhalf(0, 1);
  mfhalf(1);

  // epilogue: atomic accumulate
  // C/D 32x32: col = l&31, row = (reg&3) + 8*(reg>>2) + 4*(l>>5)
  int colb = nbase + l31;
  int rowb = mbase + 4 * lhi;
#pragma unroll
  for (int u = 0; u < 2; ++u) {
#pragma unroll
    for (int v = 0; v < 4; ++v) {
      int col = colb + v * 32;
#pragma unroll
      for (int r = 0; r < 16; ++r) {
        int row = rowb + u * 32 + (r & 3) + 8 * (r >> 2);
        atomicAdd(&h_pre[(size_t)row * HID + col], acc[u][v][r]);
      }
    }
  }
}

// ---------------- MLP layer: Y = act(X) @ W + b, col stats of Y ----------------
// W staged in LDS via gload_lds double-buffer (validated r10).
template <int FIRST>
__launch_bounds__(256, 2)
__global__ void mlp_kernel(const float* __restrict__ Xin,
                           const float* __restrict__ statsIn,
                           const float* __restrict__ gamma,
                           const float* __restrict__ beta,
                           const float* __restrict__ W,
                           const float* __restrict__ bias,
                           float* __restrict__ Yout,
                           float* __restrict__ statsOut) {
  __shared__ float Xs[4][HID];                       // 4 KB
  __shared__ __align__(16) float Wl[2][32][HID];     // 64 KB double buffer
  int br = blockIdx.x, c = threadIdx.x;
  int w = c >> 6, l = c & 63;

  // stage W tile t (rows t*32..t*32+31); wave w stages rows w*8..w*8+7
  auto stageW = [&](int t, int buf) {
    const float* src = W + ((size_t)t * 32 + w * 8) * HID + l * 4;
#pragma unroll
    for (int i = 0; i < 8; ++i)
      gload_lds16(src + (size_t)i * HID, &Wl[buf][w * 8 + i][0]);
  };

  stageW(0, 0); FENCE;                // overlap HBM/L2 latency with BN+gelu

  float mean = 0.f, rstd = 1.f, gm = 1.f, bt = 0.f;
  if (!FIRST) {
    float s1 = statsIn[c], s2 = statsIn[HID + c];
    mean = s1 * (1.0f / BATCH);
    float var = s2 * (1.0f / BATCH) - mean * mean;
    rstd = rsqrtf(var + 1e-5f);
    gm = gamma[c]; bt = beta[c];
  }
#pragma unroll
  for (int r = 0; r < 4; ++r) {
    float v = Xin[(size_t)(br * 4 + r) * HID + c];
    if (!FIRST) v = gelu_exact((v - mean) * rstd * gm + bt);
    Xs[r][c] = v;
  }
  __syncthreads();

  float acc[4] = {0.f, 0.f, 0.f, 0.f};
#pragma unroll 1
  for (int t = 0; t < 8; ++t) {
    if (t < 7) { stageW(t + 1, (t + 1) & 1); FENCE; }
    if (t < 7) { WAITV(VM8); } else { WAITV(VM0); }
    BARR;                              // tile t in for all waves
    const float* wt = &Wl[t & 1][0][0];
    int kb = t * 32;
#pragma unroll 8
    for (int kk = 0; kk < 32; ++kk) {
      float wv = wt[kk * HID + c];
#pragma unroll
      for (int r = 0; r < 4; ++r) acc[r] += Xs[r][kb + kk] * wv;
    }
    BARR;                              // reads done before stage(t+2) overwrites
  }

  float bb = bias[c];
  float s1 = 0.f, s2 = 0.f;
#pragma unroll
  for (int r = 0; r < 4; ++r) {
    float y = acc[r] + bb;
    Yout[(size_t)(br * 4 + r) * HID + c] = y;
    s1 += y; s2 += y * y;
  }
  atomicAdd(&statsOut[c], s1);
  atomicAdd(&statsOut[HID + c], s2);
}

// ---------------- final: out = gelu(bn(Y3)) @ W_out + b_out ----------------
__global__ void final_kernel(const float* __restrict__ Y3,
                             const float* __restrict__ statsIn,
                             const float* __restrict__ gamma,
                             const float* __restrict__ beta,
                             const float* __restrict__ W_out,
                             const float* __restrict__ b_out,
                             float* __restrict__ out) {
  int w = threadIdx.x >> 6, l = threadIdx.x & 63;
  int b = blockIdx.x * 4 + w;
  float4 y = *(const float4*)(Y3 + (size_t)b * HID + l * 4);
  float4 wv = *(const float4*)(W_out + l * 4);
  float r4[4] = {y.x, y.y, y.z, y.w};
  float w4[4] = {wv.x, wv.y, wv.z, wv.w};
  float s = 0.f;
  int c0 = l * 4;
#pragma unroll
  for (int q = 0; q < 4; ++q) {
    int c = c0 + q;
    float s1 = statsIn[c], s2 = statsIn[HID + c];
    float mean = s1 * (1.0f / BATCH);
    float var = s2 * (1.0f / BATCH) - mean * mean;
    float rstd = rsqrtf(var + 1e-5f);
    float v = gelu_exact((r4[q] - mean) * rstd * gamma[c] + beta[c]);
    s += v * w4[q];
  }
#pragma unroll
  for (int off = 32; off > 0; off >>= 1) s += __shfl_down(s, off);
  if (l == 0) out[b] = s + b_out[0];
}

extern "C" void kernel_launch(void* const* d_in, const int* in_sizes, int n_in,
                              void* d_out, int out_size, void* d_ws, size_t ws_size,
                              hipStream_t stream) {
  const float* x      = (const float*)d_in[0];
  const float* grids  = (const float*)d_in[1];
  const float* fs     = (const float*)d_in[2];
  const float* dscore = (const float*)d_in[3];
  const float* mlp_W  = (const float*)d_in[4];
  const float* mlp_b  = (const float*)d_in[5];
  const float* bn_g   = (const float*)d_in[6];
  const float* bn_b   = (const float*)d_in[7];
  const float* W_out  = (const float*)d_in[8];
  const float* b_out  = (const float*)d_in[9];
  float* out = (float*)d_out;

  char* ws = (char*)d_ws;
  __hip_bfloat16* fs2 = (__hip_bfloat16*)(ws + OFF_FST);
  float* z_t   = (float*)(ws + OFF_ZT);
  float* h_pre = (float*)(ws + OFF_HPRE);
  float* stats = (float*)(ws + OFF_STATS);
  u32*   keys  = (u32*)(ws + OFF_KEYS);
  float* Y1    = (float*)(ws + OFF_Y1);
  float* Y2    = (float*)(ws + OFF_Y2);
  float* Y3    = (float*)(ws + OFF_Y3);

  // zero the atomic accumulators (h_pre + BN stats + minmax keys)
  hipMemsetAsync(h_pre, 0, SZ_HPRE + SZ_STATS + SZ_KEYS, stream);

  convert_prep1_kernel<<<DEPTH * IN_DIM + 64, 256, 0, stream>>>(fs, dscore, x,
                                                                keys, fs2);
  prep2_kernel<<<32, 256, 0, stream>>>(x, keys, z_t);
  gemm_kernel<<<512, 256, 0, stream>>>(z_t, grids, fs2, h_pre);

  mlp_kernel<1><<<512, 256, 0, stream>>>(h_pre, nullptr, nullptr, nullptr,
                                         mlp_W, mlp_b, Y1, stats);
  mlp_kernel<0><<<512, 256, 0, stream>>>(Y1, stats, bn_g, bn_b,
                                         mlp_W + 65536, mlp_b + 256, Y2, stats + 512);
  mlp_kernel<0><<<512, 256, 0, stream>>>(Y2, stats + 512, bn_g + 256, bn_b + 256,
                                         mlp_W + 2 * 65536, mlp_b + 2 * 256, Y3, stats + 1024);
  final_kernel<<<512, 256, 0, stream>>>(Y3, stats + 1024, bn_g + 512, bn_b + 512,
                                        W_out, b_out, out);
}

// Round 12
// 418.453 us; speedup vs baseline: 1.0433x; 1.0433x over previous
//
#include <hip/hip_runtime.h>
#include <hip/hip_bf16.h>

#define BATCH 2048
#define IN_DIM 128
#define GRIDN 128
#define HID 256
#define DEPTH 7

typedef unsigned int u32;
typedef __attribute__((ext_vector_type(8))) short short8;
typedef __attribute__((ext_vector_type(4))) float floatx4;

// ---------------- ws layout (bytes) ----------------
// fs2: bf16, MFMA-frag-ordered: [slab:896][nhalf:2][ks:4][tt:8][l4:4][l15:16][g8:8]
#define OFF_FST   ((size_t)0)
#define SZ_FST    ((size_t)7*128*256*128*2)       // 58,720,256
#define OFF_ZT    (OFF_FST + SZ_FST)              // fp32 z_t [128][2048]
#define SZ_ZT     ((size_t)BATCH*IN_DIM*4)
#define OFF_HPRE  (OFF_ZT + SZ_ZT)                // fp32 h_pre [2048][256]
#define SZ_HPRE   ((size_t)BATCH*HID*4)
#define OFF_STATS (OFF_HPRE + SZ_HPRE)            // fp32 stats 3*[512]
#define SZ_STATS  ((size_t)3*2*HID*4)
#define OFF_KEYS  (OFF_STATS + SZ_STATS)          // u32 keys [256]
#define SZ_KEYS   ((size_t)256*4)
#define OFF_CW    (OFF_KEYS + SZ_KEYS)            // (unused now)
#define SZ_CW     ((size_t)32)
#define OFF_Y1    (OFF_CW + SZ_CW)
#define SZ_Y      ((size_t)BATCH*HID*4)
#define OFF_Y2    (OFF_Y1 + SZ_Y)
#define OFF_Y3    (OFF_Y2 + SZ_Y)

#define FENCE __asm__ volatile("" ::: "memory")
#define WAITV(c) do { __builtin_amdgcn_s_waitcnt(c); FENCE; } while (0)
#define BARR do { FENCE; __builtin_amdgcn_s_barrier(); FENCE; } while (0)
#define VM8 0x0F78
#define VM4 0x0F74
#define VM0 0x0F70

__device__ __forceinline__ void gload_lds16(const void* g, void* l) {
  __builtin_amdgcn_global_load_lds(
      (const __attribute__((address_space(1))) u32*)g,
      (__attribute__((address_space(3))) u32*)l, 16, 0, 0);
}

__device__ __forceinline__ u32 pack2_bf16(float lo, float hi) {
  __hip_bfloat162 b2;
  b2.x = __float2bfloat16(lo);
  b2.y = __float2bfloat16(hi);
  return *reinterpret_cast<u32*>(&b2);
}

// truncating bf16x2 pack: one v_perm_b32 (lo = hi16(a), hi = hi16(b))
__device__ __forceinline__ u32 pk_trunc(float a, float b) {
  return __builtin_amdgcn_perm(__float_as_uint(b), __float_as_uint(a), 0x07060302u);
}

// relu(v) for v in (-1,1): med3(v,0,1) == clamp -> folds into v_sub_f32 clamp
__device__ __forceinline__ float reluc(float v) {
  return __builtin_amdgcn_fmed3f(v, 0.0f, 1.0f);
}

__device__ __forceinline__ float gelu_exact(float x) {
  return 0.5f * x * (1.0f + erff(x * 0.70710678118654752f));
}

// ---------------- fused convert + prep1 (independent roles, one dispatch) ----
// Blocks [0,896): fs fp32 [d,i,g,h] -> cd*bf16 MFMA-frag-ordered fs2, with a
//   3x16KB triple-buffered DMA pipeline over 8 16-row phases (validated r9).
// Blocks [896,960): prep1 role — per-feature min/max monotone-key atomics.
__global__ void convert_prep1_kernel(const float* __restrict__ fs,
                                     const float* __restrict__ depth_scores,
                                     const float* __restrict__ x,
                                     u32* __restrict__ keys,
                                     __hip_bfloat16* __restrict__ fs2) {
  __shared__ __align__(16) float lds3[3 * 16 * 256];   // 48KB
  int bid = blockIdx.x;
  int t = threadIdx.x;

  if (bid >= DEPTH * IN_DIM) {
    // ---- prep1 role ----
    int pb = bid - DEPTH * IN_DIM;     // [0,64)
    int base = pb * 256 + t;
    float mn = 1e30f, mx = -1e30f;
#pragma unroll
    for (int j = 0; j < 16; ++j) {
      float v = x[base + j * 16384];   // same feature i each iter
      mn = fminf(mn, v); mx = fmaxf(mx, v);
    }
    float* smn = lds3; float* smx = lds3 + 256;
    smn[t] = mn; smx[t] = mx;
    __syncthreads();
    if (t < 128) {
      mn = fminf(smn[t], smn[t + 128]);
      mx = fmaxf(smx[t], smx[t + 128]);
      int i = base & 127;
      atomicMax(&keys[i], 0x7FFFFFFFu - __float_as_uint(mn));
      atomicMax(&keys[128 + i], __float_as_uint(mx));
    }
    return;
  }

  // ---- convert role ----
  int slab = bid;                      // d*128 + i
  int w = t >> 6, l = t & 63;
  int d = slab >> 7;
  // local softmax-cumsum: cd = sum_{i>=d} softmax(ds)[i]
  float m = -1e30f; float ds[DEPTH];
#pragma unroll
  for (int i = 0; i < DEPTH; ++i) { ds[i] = depth_scores[i]; m = fmaxf(m, ds[i]); }
  float sum = 0.f, tail = 0.f;
#pragma unroll
  for (int i = 0; i < DEPTH; ++i) {
    float e = expf(ds[i] - m);
    sum += e;
    if (i >= d) tail += e;
  }
  float cd = tail / sum;

  const float* src = fs + (size_t)slab * (GRIDN * HID);
  char* dstb = (char*)fs2 + (size_t)slab * 65536;

  // DMA phase p: global g-rows p*16 + (w*4+i) -> buf p%3 slot (w*4+i), with
  // XOR-pre-swizzled source col so lds[r][j] = fs_r[j ^ mask(r)]
  auto dmaPhase = [&](int p) {
    const float* s0 = src + (size_t)p * 16 * HID;
    char* bb = (char*)lds3 + (p % 3) * 16384;
#pragma unroll
    for (int i = 0; i < 4; ++i) {
      int sl = w * 4 + i;
      int r = p * 16 + sl;
      int mask = ((r >> 3) & 3) << 3;
      gload_lds16(s0 + (size_t)sl * HID + ((l * 4) ^ mask), bb + sl * 1024);
    }
  };
  // pack phase p (ks = p>>1, half hh = p&1): emit 512 16B-slots (2/thread)
  auto packPhase = [&](int p) {
    int ks = p >> 1, hh = p & 1;
    const float* bb = lds3 + (p % 3) * 4096;   // floats
#pragma unroll
    for (int it = 0; it < 2; ++it) {
      int task = t + it * 256;        // [0,512)
      int nhalf = task >> 8;
      int q = task & 255;
      int tt = q >> 5, l4h = (q >> 4) & 1, l15 = q & 15;
      int l4 = hh * 2 + l4h;
      int hgl = nhalf * 128 + tt * 16 + l15;
      int hx = hgl ^ (l4 << 3);       // undo source swizzle (mask(r)=(l4&3)<<3)
      const float* rp = bb + (l4h * 8) * 256 + hx;
      uint4 pk4;
      pk4.x = pack2_bf16(cd * rp[0 * 256], cd * rp[1 * 256]);
      pk4.y = pack2_bf16(cd * rp[2 * 256], cd * rp[3 * 256]);
      pk4.z = pack2_bf16(cd * rp[4 * 256], cd * rp[5 * 256]);
      pk4.w = pack2_bf16(cd * rp[6 * 256], cd * rp[7 * 256]);
      size_t off = (size_t)nhalf * 32768 + (size_t)ks * 8192 +
                   (size_t)tt * 1024 + (size_t)l4 * 256 + (size_t)l15 * 16;
      *(uint4*)(dstb + off) = pk4;
    }
  };

  dmaPhase(0); dmaPhase(1); FENCE;
#pragma unroll 1
  for (int p = 0; p < 6; ++p) {
    WAITV(VM4); BARR;                  // dma(p) in for all waves
    dmaPhase(p + 2); FENCE;            // buf (p+2)%3: last read phase p-1, safe
    packPhase(p);
  }
  WAITV(VM4); BARR; packPhase(6);
  WAITV(VM0); BARR; packPhase(7);
}

// ---------------- prep2: z_t[i][b] via LDS transpose (256B contiguous stores)
__global__ void prep2_kernel(const float* __restrict__ x, const u32* __restrict__ keys,
                             float* __restrict__ z_t) {
  __shared__ float lds[128 * 65];
  int t = threadIdx.x;
  int b0 = blockIdx.x * 64;
#pragma unroll
  for (int q = 0; q < 32; ++q) {
    int idx = q * 256 + t;              // [0, 8192)
    int b = idx >> 7, i = idx & 127;
    lds[i * 65 + b] = x[(size_t)(b0 + b) * IN_DIM + i];
  }
  __syncthreads();
#pragma unroll
  for (int q = 0; q < 32; ++q) {
    int idx = q * 256 + t;
    int ii = idx >> 6, bb = idx & 63;
    float mnv = __uint_as_float(0x7FFFFFFFu - keys[ii]);
    float mxv = __uint_as_float(keys[128 + ii]);
    float v = (lds[ii * 65 + bb] - mnv) * (1.0f / (mxv - mnv + 1e-6f));
    z_t[(size_t)ii * BATCH + b0 + bb] = v;
  }
}

// ---------------- big GEMM: h_pre += relu(z-grids) @ (c_d*fs) ----------------
// SHARED-staging TRIPLE-buffered pipeline, ONE barrier per K-step — round-7
// best config (127.5 us, MfmaUtil ~40 = 943 TF, the 2-phase plain-HIP
// structural ceiling for this shape): 512 blocks, 2/CU, wave 64Mx128N,
// 16x16x32 MFMA (32x32x16 regressed 15% — r11: longer per-wave pipe
// occupancy can't be hidden at 2 waves/SIMD).
__launch_bounds__(256, 2)
__global__ void gemm_kernel(const float* __restrict__ z_t,
                            const float* __restrict__ grids,
                            const __hip_bfloat16* __restrict__ fs2,
                            float* __restrict__ h_pre) {
  __shared__ __align__(16) char lds[24576];   // 3 x 8KB shared triple buffer

  int bx = blockIdx.x;
  int xcd = bx & 7;
  int t6 = bx >> 3;                 // [0,64)
  int cg2 = t6 >> 4;                // [0,4)
  int jb2 = t6 & 15;                // [0,16): mtile(256) * nhalf
  int chunk = xcd + 8 * cg2;        // [0,32); same-XCD blocks share fs2 chunk
  int slab0 = chunk * 28;
  int mt = jb2 >> 1;                // [0,8) 256-row mtile
  int nh = jb2 & 1;                 // n-half of output

  int tid = threadIdx.x;
  int w = tid >> 6, l = tid & 63;
  int l15 = l & 15, l4 = l >> 4;
  int mbase = mt * 256 + w * 64;    // each wave: distinct 64-row strip
  int nbase = nh * 128;

  floatx4 acc[4][8];
#pragma unroll
  for (int a = 0; a < 4; ++a)
#pragma unroll
    for (int b = 0; b < 8; ++b) acc[a][b] = (floatx4)0.f;

  // this wave's 2KB staging slice base (per-lane src; dest lane-offset is HW)
  const char* fsb = (const char*)fs2 + (size_t)slab0 * 65536 + (size_t)nh * 32768 +
                    (size_t)w * 2048 + (size_t)l * 16;

  // stage full step u (block: 8KB; this wave: 2KB = 2 x 1KB) -> buf[bufIdx]
  auto stage8 = [&](int u, int bufIdx) {
    const char* srcb = fsb + (size_t)(u >> 2) * 65536 + (size_t)(u & 3) * 8192;
    char* dst = lds + bufIdx * 8192 + w * 2048;
    gload_lds16(srcb, dst);
    gload_lds16(srcb + 1024, dst + 1024);
  };

  float4 zA, zB;                    // z regs, parity by step (even=A, odd=B)
  float4 g0A, g1A, g0B, g1B;
  auto zgload = [&](int s, float4& zv, float4& G0, float4& G1) {
    int slab = slab0 + (s >> 2);
    int iz = slab & 127;
    const float* zp = z_t + (size_t)iz * BATCH + mbase + l15;
    zv.x = zp[0]; zv.y = zp[16]; zv.z = zp[32]; zv.w = zp[48];
    const float* gp = grids + (size_t)slab * GRIDN + (s & 3) * 32 + l4 * 8;
    G0 = *(const float4*)gp;
    G1 = *(const float4*)(gp + 4);
  };

  short8 af[4];
  short8 bf[8];
  auto rdfrag8 = [&](int bufIdx) {
    const char* bp = lds + bufIdx * 8192 + l * 16;
#pragma unroll
    for (int tt = 0; tt < 8; ++tt)
      bf[tt] = *(const short8*)(bp + tt * 1024);
  };
  // A fragments: relu(z - grid) via sub+clamp, truncating bf16 pack
  auto afgen = [&](const float4 zv, const float4 G0, const float4 G1) {
#pragma unroll
    for (int u = 0; u < 4; ++u) {
      float zu = (u == 0) ? zv.x : (u == 1) ? zv.y : (u == 2) ? zv.z : zv.w;
      union { uint4 q; short8 s8; } pk;
      pk.q.x = pk_trunc(reluc(zu - G0.x), reluc(zu - G0.y));
      pk.q.y = pk_trunc(reluc(zu - G0.z), reluc(zu - G0.w));
      pk.q.z = pk_trunc(reluc(zu - G1.x), reluc(zu - G1.y));
      pk.q.w = pk_trunc(reluc(zu - G1.z), reluc(zu - G1.w));
      af[u] = pk.s8;
    }
  };
  auto mfma32 = [&]() {
    __builtin_amdgcn_s_setprio(1);
#pragma unroll
    for (int u = 0; u < 4; ++u)
#pragma unroll
      for (int tt = 0; tt < 8; ++tt)
        acc[u][tt] = __builtin_amdgcn_mfma_f32_16x16x32_bf16(af[u], bf[tt], acc[u][tt], 0, 0, 0);
    __builtin_amdgcn_s_setprio(0);
  };

// full step: wait own slices+zg of step S -> barrier (all waves' slices in),
// stage S+2, ds_read frags, gen A (hides LDS latency), prefetch zg(S+2), MFMA.
#define STEP_FULL(S, BUF, STBUF, ZV, G0, G1)                                   \
  do {                                                                         \
    WAITV(VM8); BARR;                                                          \
    stage8((S) + 2, (STBUF)); FENCE;                                           \
    rdfrag8(BUF);                                                              \
    afgen(ZV, G0, G1);                                                         \
    zgload((S) + 2, ZV, G0, G1); FENCE;                                        \
    mfma32();                                                                  \
  } while (0)

  // prologue: queue = [St0:2, Zg0:6, St1:2, Zg1:6] = 16 in flight
  stage8(0, 0); FENCE;
  zgload(0, zA, g0A, g1A); FENCE;
  stage8(1, 1); FENCE;
  zgload(1, zB, g0B, g1B); FENCE;

  // main loop: steps 0..107, buf = s%3, zg parity = s%2; uniform vmcnt(8)
#pragma unroll 1
  for (int s0 = 0; s0 < 108; s0 += 6) {
    STEP_FULL(s0 + 0, 0, 2, zA, g0A, g1A);
    STEP_FULL(s0 + 1, 1, 0, zB, g0B, g1B);
    STEP_FULL(s0 + 2, 2, 1, zA, g0A, g1A);
    STEP_FULL(s0 + 3, 0, 2, zB, g0B, g1B);
    STEP_FULL(s0 + 4, 1, 0, zA, g0A, g1A);
    STEP_FULL(s0 + 5, 2, 1, zB, g0B, g1B);
  }

  // ---- tail ----
  STEP_FULL(108, 0, 2, zA, g0A, g1A);
  STEP_FULL(109, 1, 0, zB, g0B, g1B);
  WAITV(VM8); BARR;
  rdfrag8(2);
  afgen(zA, g0A, g1A);
  mfma32();
  WAITV(VM0); BARR;
  rdfrag8(0);
  afgen(zB, g0B, g1B);
  mfma32();

  // epilogue: atomic accumulate (C/D: col=l&15, row=(l>>4)*4+r)
  int row0 = mbase + l4 * 4;
  int col0 = nbase + l15;
#pragma unroll
  for (int u = 0; u < 4; ++u) {
#pragma unroll
    for (int tt = 0; tt < 8; ++tt) {
      int col = col0 + tt * 16;
#pragma unroll
      for (int r = 0; r < 4; ++r) {
        int row = row0 + u * 16 + r;
        atomicAdd(&h_pre[(size_t)row * HID + col], acc[u][tt][r]);
      }
    }
  }
}

// ---------------- MLP layer: Y = act(X) @ W + b, col stats of Y ----------------
// W staged in LDS via gload_lds double-buffer (validated r10: -4.5 us).
template <int FIRST>
__launch_bounds__(256, 2)
__global__ void mlp_kernel(const float* __restrict__ Xin,
                           const float* __restrict__ statsIn,
                           const float* __restrict__ gamma,
                           const float* __restrict__ beta,
                           const float* __restrict__ W,
                           const float* __restrict__ bias,
                           float* __restrict__ Yout,
                           float* __restrict__ statsOut) {
  __shared__ float Xs[4][HID];                       // 4 KB
  __shared__ __align__(16) float Wl[2][32][HID];     // 64 KB double buffer
  int br = blockIdx.x, c = threadIdx.x;
  int w = c >> 6, l = c & 63;

  // stage W tile t (rows t*32..t*32+31); wave w stages rows w*8..w*8+7
  auto stageW = [&](int t, int buf) {
    const float* src = W + ((size_t)t * 32 + w * 8) * HID + l * 4;
#pragma unroll
    for (int i = 0; i < 8; ++i)
      gload_lds16(src + (size_t)i * HID, &Wl[buf][w * 8 + i][0]);
  };

  stageW(0, 0); FENCE;                // overlap HBM/L2 latency with BN+gelu

  float mean = 0.f, rstd = 1.f, gm = 1.f, bt = 0.f;
  if (!FIRST) {
    float s1 = statsIn[c], s2 = statsIn[HID + c];
    mean = s1 * (1.0f / BATCH);
    float var = s2 * (1.0f / BATCH) - mean * mean;
    rstd = rsqrtf(var + 1e-5f);
    gm = gamma[c]; bt = beta[c];
  }
#pragma unroll
  for (int r = 0; r < 4; ++r) {
    float v = Xin[(size_t)(br * 4 + r) * HID + c];
    if (!FIRST) v = gelu_exact((v - mean) * rstd * gm + bt);
    Xs[r][c] = v;
  }
  __syncthreads();

  float acc[4] = {0.f, 0.f, 0.f, 0.f};
#pragma unroll 1
  for (int t = 0; t < 8; ++t) {
    if (t < 7) { stageW(t + 1, (t + 1) & 1); FENCE; }
    if (t < 7) { WAITV(VM8); } else { WAITV(VM0); }
    BARR;                              // tile t in for all waves
    const float* wt = &Wl[t & 1][0][0];
    int kb = t * 32;
#pragma unroll 8
    for (int kk = 0; kk < 32; ++kk) {
      float wv = wt[kk * HID + c];
#pragma unroll
      for (int r = 0; r < 4; ++r) acc[r] += Xs[r][kb + kk] * wv;
    }
    BARR;                              // reads done before stage(t+2) overwrites
  }

  float bb = bias[c];
  float s1 = 0.f, s2 = 0.f;
#pragma unroll
  for (int r = 0; r < 4; ++r) {
    float y = acc[r] + bb;
    Yout[(size_t)(br * 4 + r) * HID + c] = y;
    s1 += y; s2 += y * y;
  }
  atomicAdd(&statsOut[c], s1);
  atomicAdd(&statsOut[HID + c], s2);
}

// ---------------- final: out = gelu(bn(Y3)) @ W_out + b_out ----------------
__global__ void final_kernel(const float* __restrict__ Y3,
                             const float* __restrict__ statsIn,
                             const float* __restrict__ gamma,
                             const float* __restrict__ beta,
                             const float* __restrict__ W_out,
                             const float* __restrict__ b_out,
                             float* __restrict__ out) {
  int w = threadIdx.x >> 6, l = threadIdx.x & 63;
  int b = blockIdx.x * 4 + w;
  float4 y = *(const float4*)(Y3 + (size_t)b * HID + l * 4);
  float4 wv = *(const float4*)(W_out + l * 4);
  float r4[4] = {y.x, y.y, y.z, y.w};
  float w4[4] = {wv.x, wv.y, wv.z, wv.w};
  float s = 0.f;
  int c0 = l * 4;
#pragma unroll
  for (int q = 0; q < 4; ++q) {
    int c = c0 + q;
    float s1 = statsIn[c], s2 = statsIn[HID + c];
    float mean = s1 * (1.0f / BATCH);
    float var = s2 * (1.0f / BATCH) - mean * mean;
    float rstd = rsqrtf(var + 1e-5f);
    float v = gelu_exact((r4[q] - mean) * rstd * gamma[c] + beta[c]);
    s += v * w4[q];
  }
#pragma unroll
  for (int off = 32; off > 0; off >>= 1) s += __shfl_down(s, off);
  if (l == 0) out[b] = s + b_out[0];
}

extern "C" void kernel_launch(void* const* d_in, const int* in_sizes, int n_in,
                              void* d_out, int out_size, void* d_ws, size_t ws_size,
                              hipStream_t stream) {
  const float* x      = (const float*)d_in[0];
  const float* grids  = (const float*)d_in[1];
  const float* fs     = (const float*)d_in[2];
  const float* dscore = (const float*)d_in[3];
  const float* mlp_W  = (const float*)d_in[4];
  const float* mlp_b  = (const float*)d_in[5];
  const float* bn_g   = (const float*)d_in[6];
  const float* bn_b   = (const float*)d_in[7];
  const float* W_out  = (const float*)d_in[8];
  const float* b_out  = (const float*)d_in[9];
  float* out = (float*)d_out;

  char* ws = (char*)d_ws;
  __hip_bfloat16* fs2 = (__hip_bfloat16*)(ws + OFF_FST);
  float* z_t   = (float*)(ws + OFF_ZT);
  float* h_pre = (float*)(ws + OFF_HPRE);
  float* stats = (float*)(ws + OFF_STATS);
  u32*   keys  = (u32*)(ws + OFF_KEYS);
  float* Y1    = (float*)(ws + OFF_Y1);
  float* Y2    = (float*)(ws + OFF_Y2);
  float* Y3    = (float*)(ws + OFF_Y3);

  // zero the atomic accumulators (h_pre + BN stats + minmax keys)
  hipMemsetAsync(h_pre, 0, SZ_HPRE + SZ_STATS + SZ_KEYS, stream);

  convert_prep1_kernel<<<DEPTH * IN_DIM + 64, 256, 0, stream>>>(fs, dscore, x,
                                                                keys, fs2);
  prep2_kernel<<<32, 256, 0, stream>>>(x, keys, z_t);
  gemm_kernel<<<512, 256, 0, stream>>>(z_t, grids, fs2, h_pre);

  mlp_kernel<1><<<512, 256, 0, stream>>>(h_pre, nullptr, nullptr, nullptr,
                                         mlp_W, mlp_b, Y1, stats);
  mlp_kernel<0><<<512, 256, 0, stream>>>(Y1, stats, bn_g, bn_b,
                                         mlp_W + 65536, mlp_b + 256, Y2, stats + 512);
  mlp_kernel<0><<<512, 256, 0, stream>>>(Y2, stats + 512, bn_g + 256, bn_b + 256,
                                         mlp_W + 2 * 65536, mlp_b + 2 * 256, Y3, stats + 1024);
  final_kernel<<<512, 256, 0, stream>>>(Y3, stats + 1024, bn_g + 512, bn_b + 512,
                                        W_out, b_out, out);
}